// Round 21
// baseline (446.341 us; speedup 1.0000x reference)
//
// v20: v19 base; ONLY k1 change = P aliases the Ks buffer (K dead after QK^T),
//      +1 barrier between QK^T and P-write. LDS 24->16KB -> 8 blocks/CU =
//      32 waves/CU (max). k2 = v6 verbatim.
#include <hip/hip_runtime.h>

#define S_LEN 2048
#define D_KD  64
#define NKT   32          // S / 64 k-tiles
#define NBH   64          // B*H
#define KSEG  4           // kernel2: key segments per (bh,qt)

typedef __attribute__((ext_vector_type(8))) short short8;   // 8 bf16 (4 VGPRs)
typedef __attribute__((ext_vector_type(4))) float f32x4;    // MFMA C/D

// ---- bf16 round-to-nearest-even from f32 ----
__device__ __forceinline__ unsigned short f2bf(float f) {
    unsigned u = __builtin_bit_cast(unsigned, f);
    return (unsigned short)((u + 0x7fffu + ((u >> 16) & 1u)) >> 16);
}
__device__ __forceinline__ short8 pack8(float4 a, float4 b) {
    short8 r;
    r[0] = (short)f2bf(a.x); r[1] = (short)f2bf(a.y);
    r[2] = (short)f2bf(a.z); r[3] = (short)f2bf(a.w);
    r[4] = (short)f2bf(b.x); r[5] = (short)f2bf(b.y);
    r[6] = (short)f2bf(b.z); r[7] = (short)f2bf(b.w);
    return r;
}

// Cross-wave LDS-visibility barrier WITHOUT vmcnt drain.
__device__ __forceinline__ void ldsbar() {
    asm volatile("s_waitcnt lgkmcnt(0)" ::: "memory");
    __builtin_amdgcn_s_barrier();
}
// Wave-local LDS ordering only (producer == consumer wave).
__device__ __forceinline__ void ldswait() {
    asm volatile("s_waitcnt lgkmcnt(0)" ::: "memory");
    __builtin_amdgcn_sched_barrier(0);
}

// ---- XOR swizzle for [64][64] bf16 tiles (row stride 128B).
__device__ __forceinline__ unsigned swz(int row, int bytecol) {
    return (unsigned)(row * 128 + bytecol) ^
           (((((unsigned)row & 7u) ^ ((unsigned)row >> 3)) & 7u) << 4);
}

// ---- register-staged tile load/write (256-thread) ----
__device__ __forceinline__ void load_rm(const float* __restrict__ g,
                                        float4 r[4], int tid) {
#pragma unroll
    for (int j = 0; j < 4; j++) r[j] = *(const float4*)(g + j * 1024 + tid * 4);
}
__device__ __forceinline__ void write_rm(const float4 r[4],
                                         unsigned char* lds, int tid) {
#pragma unroll
    for (int j = 0; j < 4; j++) {
        int idx = j * 1024 + tid * 4;
        int row = idx >> 6, col = idx & 63;
        ushort4 b = make_ushort4(f2bf(r[j].x), f2bf(r[j].y), f2bf(r[j].z), f2bf(r[j].w));
        *(ushort4*)(lds + swz(row, col * 2)) = b;
    }
}
__device__ __forceinline__ void load_tr(const float* __restrict__ g,
                                        float4 r[4], int tid) {
    const int br = tid >> 4, bc = tid & 15;
    const float* gp = g + (4 * br) * 64 + 4 * bc;
#pragma unroll
    for (int j = 0; j < 4; j++) r[j] = *(const float4*)(gp + j * 64);
}
__device__ __forceinline__ void write_tr(const float4 r[4],
                                         unsigned char* lds, int tid) {
    const int br = tid >> 4, bc = tid & 15;
    ushort4 c;
    c = make_ushort4(f2bf(r[0].x), f2bf(r[1].x), f2bf(r[2].x), f2bf(r[3].x));
    *(ushort4*)(lds + swz(4 * bc + 0, 8 * br)) = c;
    c = make_ushort4(f2bf(r[0].y), f2bf(r[1].y), f2bf(r[2].y), f2bf(r[3].y));
    *(ushort4*)(lds + swz(4 * bc + 1, 8 * br)) = c;
    c = make_ushort4(f2bf(r[0].z), f2bf(r[1].z), f2bf(r[2].z), f2bf(r[3].z));
    *(ushort4*)(lds + swz(4 * bc + 2, 8 * br)) = c;
    c = make_ushort4(f2bf(r[0].w), f2bf(r[1].w), f2bf(r[2].w), f2bf(r[3].w));
    *(ushort4*)(lds + swz(4 * bc + 3, 8 * br)) = c;
}
__device__ __forceinline__ void stage_rm(const float* __restrict__ g,
                                         unsigned char* lds, int tid) {
    float4 r[4];
    load_rm(g, r, tid);
    write_rm(r, lds, tid);
}

// QK^T with Q in registers (kernel 1).
__device__ __forceinline__ void qkt_r(short8 qa0, short8 qa1, const unsigned char* Ks,
                                      int lr, int lg, f32x4 acc[4]) {
#pragma unroll
    for (int nt = 0; nt < 4; nt++) {
        short8 b0 = *(const short8*)(Ks + swz(16 * nt + lr, 16 * lg));
        short8 b1 = *(const short8*)(Ks + swz(16 * nt + lr, 16 * lg + 64));
        acc[nt] = __builtin_amdgcn_mfma_f32_16x16x32_bf16(qa0, b0, acc[nt], 0, 0, 0);
        acc[nt] = __builtin_amdgcn_mfma_f32_16x16x32_bf16(qa1, b1, acc[nt], 0, 0, 0);
    }
}
// 64x64 QK^T, Q from LDS (kernel 2).
__device__ __forceinline__ void qkt(const unsigned char* Qs, const unsigned char* Ks,
                                    int wv, int lr, int lg, f32x4 acc[4]) {
    short8 a0 = *(const short8*)(Qs + swz(16 * wv + lr, 16 * lg));
    short8 a1 = *(const short8*)(Qs + swz(16 * wv + lr, 16 * lg + 64));
#pragma unroll
    for (int nt = 0; nt < 4; nt++) {
        short8 b0 = *(const short8*)(Ks + swz(16 * nt + lr, 16 * lg));
        short8 b1 = *(const short8*)(Ks + swz(16 * nt + lr, 16 * lg + 64));
        acc[nt] = __builtin_amdgcn_mfma_f32_16x16x32_bf16(a0, b0, acc[nt], 0, 0, 0);
        acc[nt] = __builtin_amdgcn_mfma_f32_16x16x32_bf16(a1, b1, acc[nt], 0, 0, 0);
    }
}

// ---------------- kernel 1: context + inverse rowsums ----------------
__global__ __launch_bounds__(256) void attn_ctx(
    const float* __restrict__ Q, const float* __restrict__ K,
    const float* __restrict__ V, const float* __restrict__ M,
    float* __restrict__ out, float* __restrict__ invg) {
    __shared__ unsigned char KP[8192];   // K tile during QK^T, then P tile
    __shared__ unsigned char Vs[8192];   // transposed: [dcol][key]

    const int tid = threadIdx.x;
    const int wv = tid >> 6, lane = tid & 63, lr = lane & 15, lg = lane >> 4;
    // XCD-aware remap (v11): XCD = blk%8 gets bh 8*(blk%8) .. +7.
    const int blk = blockIdx.x;
    const int bh = (blk & 7) * 8 + (blk >> 8);
    const int qt = (blk >> 3) & 31;

    const float* Kg = K + (size_t)bh * S_LEN * D_KD;
    const float* Vg = V + (size_t)bh * S_LEN * D_KD;
    float* ctxg = out + ((size_t)bh * S_LEN + qt * 64) * D_KD;
    const float* Mg = M + (size_t)(qt * 64) * S_LEN;  // mask broadcast over bh

    // Q A-fragment in registers (one-time; exact MFMA A layout)
    short8 qa0, qa1;
    {
        const float* qr = Q + ((size_t)bh * S_LEN + qt * 64 + 16 * wv + lr) * D_KD + 8 * lg;
        qa0 = pack8(*(const float4*)(qr), *(const float4*)(qr + 4));
        qa1 = pack8(*(const float4*)(qr + 32), *(const float4*)(qr + 36));
    }

    f32x4 accc[4] = {};
    float rs[4] = {0.f, 0.f, 0.f, 0.f};

    float4 kreg[4], vreg[4];
    load_rm(Kg, kreg, tid);
    load_tr(Vg, vreg, tid);

    for (int t = 0; t < NKT; t++) {
        write_rm(kreg, KP, tid);
        write_tr(vreg, Vs, tid);
        ldsbar();                             // (1) staging visible

        if (t + 1 < NKT) {
            load_rm(Kg + (size_t)(t + 1) * 64 * D_KD, kreg, tid);
            load_tr(Vg + (size_t)(t + 1) * 64 * D_KD, vreg, tid);
        }

        float mreg[4][4];
#pragma unroll
        for (int r = 0; r < 4; r++) {
            const float* mrow = Mg + (size_t)(16 * wv + 4 * lg + r) * S_LEN + t * 64;
#pragma unroll
            for (int nt = 0; nt < 4; nt++) mreg[r][nt] = mrow[16 * nt + lr];
        }

        f32x4 acc[4] = {};
        qkt_r(qa0, qa1, KP, lr, lg, acc);
        ldsbar();                             // (2) all QK^T reads done: KP -> P

#pragma unroll
        for (int r = 0; r < 4; r++) {
            const int row = 16 * wv + 4 * lg + r;
#pragma unroll
            for (int nt = 0; nt < 4; nt++) {
                float e = __expf(acc[nt][r] * 0.125f) * mreg[r][nt];
                rs[r] += e;
                *(unsigned short*)(KP + swz(row, (16 * nt + lr) * 2)) = f2bf(e);
            }
        }
        ldswait();   // P rows are wave-private: wave-local ordering suffices

#pragma unroll
        for (int kt = 0; kt < 2; kt++) {
            short8 pa = *(const short8*)(KP + swz(16 * wv + lr, 16 * lg + 64 * kt));
#pragma unroll
            for (int nt = 0; nt < 4; nt++) {
                short8 vb = *(const short8*)(Vs + swz(16 * nt + lr, 16 * lg + 64 * kt));
                accc[nt] = __builtin_amdgcn_mfma_f32_16x16x32_bf16(pa, vb, accc[nt], 0, 0, 0);
            }
        }
        ldsbar();                             // (3) PV reads done before next staging
    }

    float inv[4];
#pragma unroll
    for (int r = 0; r < 4; r++) {
        float v = rs[r];
        v += __shfl_xor(v, 1);
        v += __shfl_xor(v, 2);
        v += __shfl_xor(v, 4);
        v += __shfl_xor(v, 8);
        inv[r] = 1.0f / (v + 1e-8f);
    }

#pragma unroll
    for (int r = 0; r < 4; r++) {
        const int row = 16 * wv + 4 * lg + r;
#pragma unroll
        for (int nt = 0; nt < 4; nt++)
            ctxg[(size_t)row * D_KD + 16 * nt + lr] = accc[nt][r] * inv[r];
    }

    if (lr == 0) {
#pragma unroll
        for (int r = 0; r < 4; r++)
            invg[(size_t)bh * S_LEN + qt * 64 + 16 * wv + 4 * lg + r] = inv[r];
    }
}

// ---------------- kernel 2: stream normalized attn (v6 verbatim) ----------------
__global__ __launch_bounds__(256) void attn_mat(
    const float* __restrict__ Q, const float* __restrict__ K,
    const float* __restrict__ M, const float* __restrict__ invg,
    float* __restrict__ out) {
    __shared__ unsigned char Qs[8192];
    __shared__ unsigned char Ks[8192];

    const int tid = threadIdx.x;
    const int wv = tid >> 6, lane = tid & 63, lr = lane & 15, lg = lane >> 4;
    const int ks = blockIdx.x & (KSEG - 1);
    const int qt = (blockIdx.x >> 2) & 31;
    const int bh = blockIdx.x >> 7;

    const float* Qg = Q + ((size_t)bh * S_LEN + qt * 64) * D_KD;
    const float* Kg = K + (size_t)bh * S_LEN * D_KD;
    const float* Mg = M + (size_t)(qt * 64) * S_LEN;
    float* attng = out + (size_t)NBH * S_LEN * D_KD +
                   (size_t)bh * S_LEN * S_LEN + (size_t)(qt * 64) * S_LEN;

    stage_rm(Qg, Qs, tid);

    float inv[4];
#pragma unroll
    for (int r = 0; r < 4; r++)
        inv[r] = invg[(size_t)bh * S_LEN + qt * 64 + 16 * wv + 4 * lg + r];

    const int nt_kt = S_LEN / (64 * KSEG);   // 8 k-tiles per block
    const float* Kseg = Kg + (size_t)(ks * (S_LEN / KSEG)) * D_KD;

    float4 kreg[4];
    load_rm(Kseg, kreg, tid);                // prologue prefetch

    for (int kt = 0; kt < nt_kt; kt++) {
        const int key0 = ks * (S_LEN / KSEG) + kt * 64;
        write_rm(kreg, Ks, tid);             // consume prefetch
        ldsbar();                            // staging visible; stores keep flying

        if (kt + 1 < nt_kt)
            load_rm(Kseg + (size_t)(kt + 1) * 64 * D_KD, kreg, tid);

        float mreg[4][4];
#pragma unroll
        for (int r = 0; r < 4; r++) {
            const float* mrow = Mg + (size_t)(16 * wv + 4 * lg + r) * S_LEN + key0;
#pragma unroll
            for (int nt = 0; nt < 4; nt++) mreg[r][nt] = mrow[16 * nt + lr];
        }

        f32x4 acc[4] = {};
        qkt(Qs, Ks, wv, lr, lg, acc);

#pragma unroll
        for (int r = 0; r < 4; r++) {
            const int row = 16 * wv + 4 * lg + r;
            float* arow = attng + (size_t)row * S_LEN + key0;
#pragma unroll
            for (int nt = 0; nt < 4; nt++) {
                float e = __expf(acc[nt][r] * 0.125f) * mreg[r][nt] * inv[r];
                __builtin_nontemporal_store(e, arow + 16 * nt + lr);
            }
        }
        ldsbar();                            // qkt ds_reads done before overwrite
    }
}

extern "C" void kernel_launch(void* const* d_in, const int* in_sizes, int n_in,
                              void* d_out, int out_size, void* d_ws, size_t ws_size,
                              hipStream_t stream) {
    const float* Q = (const float*)d_in[0];
    const float* K = (const float*)d_in[1];
    const float* V = (const float*)d_in[2];
    const float* M = (const float*)d_in[3];
    float* out = (float*)d_out;
    float* invg = (float*)d_ws;          // 64*2048 floats = 512 KB
    attn_ctx<<<dim3(NBH * 32), dim3(256), 0, stream>>>(Q, K, V, M, out, invg);
    attn_mat<<<dim3(NBH * 32 * KSEG), dim3(256), 0, stream>>>(Q, K, M, invg, out);
}

// Round 22
// 432.631 us; speedup vs baseline: 1.0317x; 1.0317x over previous
//
// v21: k1 = v19 verbatim (436.6us best). k2 = v6 structure but Q in registers
//      (no Qs LDS, no per-tile Q fragment ds_reads); LDS 16->8KB.
#include <hip/hip_runtime.h>

#define S_LEN 2048
#define D_KD  64
#define NKT   32          // S / 64 k-tiles
#define NBH   64          // B*H
#define KSEG  4           // kernel2: key segments per (bh,qt)

typedef __attribute__((ext_vector_type(8))) short short8;   // 8 bf16 (4 VGPRs)
typedef __attribute__((ext_vector_type(4))) float f32x4;    // MFMA C/D

// ---- bf16 round-to-nearest-even from f32 ----
__device__ __forceinline__ unsigned short f2bf(float f) {
    unsigned u = __builtin_bit_cast(unsigned, f);
    return (unsigned short)((u + 0x7fffu + ((u >> 16) & 1u)) >> 16);
}
__device__ __forceinline__ short8 pack8(float4 a, float4 b) {
    short8 r;
    r[0] = (short)f2bf(a.x); r[1] = (short)f2bf(a.y);
    r[2] = (short)f2bf(a.z); r[3] = (short)f2bf(a.w);
    r[4] = (short)f2bf(b.x); r[5] = (short)f2bf(b.y);
    r[6] = (short)f2bf(b.z); r[7] = (short)f2bf(b.w);
    return r;
}

// Cross-wave LDS-visibility barrier WITHOUT vmcnt drain.
__device__ __forceinline__ void ldsbar() {
    asm volatile("s_waitcnt lgkmcnt(0)" ::: "memory");
    __builtin_amdgcn_s_barrier();
}
// Wave-local LDS ordering only (producer == consumer wave).
__device__ __forceinline__ void ldswait() {
    asm volatile("s_waitcnt lgkmcnt(0)" ::: "memory");
    __builtin_amdgcn_sched_barrier(0);
}

// ---- XOR swizzle for [64][64] bf16 tiles (row stride 128B).
__device__ __forceinline__ unsigned swz(int row, int bytecol) {
    return (unsigned)(row * 128 + bytecol) ^
           (((((unsigned)row & 7u) ^ ((unsigned)row >> 3)) & 7u) << 4);
}

// ---- register-staged tile load/write (256-thread) ----
__device__ __forceinline__ void load_rm(const float* __restrict__ g,
                                        float4 r[4], int tid) {
#pragma unroll
    for (int j = 0; j < 4; j++) r[j] = *(const float4*)(g + j * 1024 + tid * 4);
}
__device__ __forceinline__ void write_rm(const float4 r[4],
                                         unsigned char* lds, int tid) {
#pragma unroll
    for (int j = 0; j < 4; j++) {
        int idx = j * 1024 + tid * 4;
        int row = idx >> 6, col = idx & 63;
        ushort4 b = make_ushort4(f2bf(r[j].x), f2bf(r[j].y), f2bf(r[j].z), f2bf(r[j].w));
        *(ushort4*)(lds + swz(row, col * 2)) = b;
    }
}
__device__ __forceinline__ void load_tr(const float* __restrict__ g,
                                        float4 r[4], int tid) {
    const int br = tid >> 4, bc = tid & 15;
    const float* gp = g + (4 * br) * 64 + 4 * bc;
#pragma unroll
    for (int j = 0; j < 4; j++) r[j] = *(const float4*)(gp + j * 64);
}
__device__ __forceinline__ void write_tr(const float4 r[4],
                                         unsigned char* lds, int tid) {
    const int br = tid >> 4, bc = tid & 15;
    ushort4 c;
    c = make_ushort4(f2bf(r[0].x), f2bf(r[1].x), f2bf(r[2].x), f2bf(r[3].x));
    *(ushort4*)(lds + swz(4 * bc + 0, 8 * br)) = c;
    c = make_ushort4(f2bf(r[0].y), f2bf(r[1].y), f2bf(r[2].y), f2bf(r[3].y));
    *(ushort4*)(lds + swz(4 * bc + 1, 8 * br)) = c;
    c = make_ushort4(f2bf(r[0].z), f2bf(r[1].z), f2bf(r[2].z), f2bf(r[3].z));
    *(ushort4*)(lds + swz(4 * bc + 2, 8 * br)) = c;
    c = make_ushort4(f2bf(r[0].w), f2bf(r[1].w), f2bf(r[2].w), f2bf(r[3].w));
    *(ushort4*)(lds + swz(4 * bc + 3, 8 * br)) = c;
}

// QK^T with Q in registers.
__device__ __forceinline__ void qkt_r(short8 qa0, short8 qa1, const unsigned char* Ks,
                                      int lr, int lg, f32x4 acc[4]) {
#pragma unroll
    for (int nt = 0; nt < 4; nt++) {
        short8 b0 = *(const short8*)(Ks + swz(16 * nt + lr, 16 * lg));
        short8 b1 = *(const short8*)(Ks + swz(16 * nt + lr, 16 * lg + 64));
        acc[nt] = __builtin_amdgcn_mfma_f32_16x16x32_bf16(qa0, b0, acc[nt], 0, 0, 0);
        acc[nt] = __builtin_amdgcn_mfma_f32_16x16x32_bf16(qa1, b1, acc[nt], 0, 0, 0);
    }
}

// ---------------- kernel 1: context + inverse rowsums (v19 verbatim) ----------------
__global__ __launch_bounds__(256) void attn_ctx(
    const float* __restrict__ Q, const float* __restrict__ K,
    const float* __restrict__ V, const float* __restrict__ M,
    float* __restrict__ out, float* __restrict__ invg) {
    __shared__ unsigned char Ks[8192];
    __shared__ unsigned char Vs[8192];   // transposed: [dcol][key]
    __shared__ unsigned char Ps[8192];

    const int tid = threadIdx.x;
    const int wv = tid >> 6, lane = tid & 63, lr = lane & 15, lg = lane >> 4;
    // XCD-aware remap (v11): XCD = blk%8 gets bh 8*(blk%8) .. +7.
    const int blk = blockIdx.x;
    const int bh = (blk & 7) * 8 + (blk >> 8);
    const int qt = (blk >> 3) & 31;

    const float* Kg = K + (size_t)bh * S_LEN * D_KD;
    const float* Vg = V + (size_t)bh * S_LEN * D_KD;
    float* ctxg = out + ((size_t)bh * S_LEN + qt * 64) * D_KD;
    const float* Mg = M + (size_t)(qt * 64) * S_LEN;  // mask broadcast over bh

    // Q A-fragment in registers (one-time; exact MFMA A layout)
    short8 qa0, qa1;
    {
        const float* qr = Q + ((size_t)bh * S_LEN + qt * 64 + 16 * wv + lr) * D_KD + 8 * lg;
        qa0 = pack8(*(const float4*)(qr), *(const float4*)(qr + 4));
        qa1 = pack8(*(const float4*)(qr + 32), *(const float4*)(qr + 36));
    }

    f32x4 accc[4] = {};
    float rs[4] = {0.f, 0.f, 0.f, 0.f};

    float4 kreg[4], vreg[4];
    load_rm(Kg, kreg, tid);
    load_tr(Vg, vreg, tid);

    for (int t = 0; t < NKT; t++) {
        write_rm(kreg, Ks, tid);
        write_tr(vreg, Vs, tid);
        ldsbar();                             // staging visible; vm stays in flight

        if (t + 1 < NKT) {
            load_rm(Kg + (size_t)(t + 1) * 64 * D_KD, kreg, tid);
            load_tr(Vg + (size_t)(t + 1) * 64 * D_KD, vreg, tid);
        }

        float mreg[4][4];
#pragma unroll
        for (int r = 0; r < 4; r++) {
            const float* mrow = Mg + (size_t)(16 * wv + 4 * lg + r) * S_LEN + t * 64;
#pragma unroll
            for (int nt = 0; nt < 4; nt++) mreg[r][nt] = mrow[16 * nt + lr];
        }

        f32x4 acc[4] = {};
        qkt_r(qa0, qa1, Ks, lr, lg, acc);

#pragma unroll
        for (int r = 0; r < 4; r++) {
            const int row = 16 * wv + 4 * lg + r;
#pragma unroll
            for (int nt = 0; nt < 4; nt++) {
                float e = __expf(acc[nt][r] * 0.125f) * mreg[r][nt];
                rs[r] += e;
                *(unsigned short*)(Ps + swz(row, (16 * nt + lr) * 2)) = f2bf(e);
            }
        }
        ldswait();   // P is wave-private

#pragma unroll
        for (int kt = 0; kt < 2; kt++) {
            short8 pa = *(const short8*)(Ps + swz(16 * wv + lr, 16 * lg + 64 * kt));
#pragma unroll
            for (int nt = 0; nt < 4; nt++) {
                short8 vb = *(const short8*)(Vs + swz(16 * nt + lr, 16 * lg + 64 * kt));
                accc[nt] = __builtin_amdgcn_mfma_f32_16x16x32_bf16(pa, vb, accc[nt], 0, 0, 0);
            }
        }
        ldsbar();                             // all reads done before next overwrite
    }

    float inv[4];
#pragma unroll
    for (int r = 0; r < 4; r++) {
        float v = rs[r];
        v += __shfl_xor(v, 1);
        v += __shfl_xor(v, 2);
        v += __shfl_xor(v, 4);
        v += __shfl_xor(v, 8);
        inv[r] = 1.0f / (v + 1e-8f);
    }

#pragma unroll
    for (int r = 0; r < 4; r++) {
        const int row = 16 * wv + 4 * lg + r;
#pragma unroll
        for (int nt = 0; nt < 4; nt++)
            ctxg[(size_t)row * D_KD + 16 * nt + lr] = accc[nt][r] * inv[r];
    }

    if (lr == 0) {
#pragma unroll
        for (int r = 0; r < 4; r++)
            invg[(size_t)bh * S_LEN + qt * 64 + 16 * wv + 4 * lg + r] = inv[r];
    }
}

// ---------------- kernel 2: stream normalized attn (Q in registers) ----------------
__global__ __launch_bounds__(256) void attn_mat(
    const float* __restrict__ Q, const float* __restrict__ K,
    const float* __restrict__ M, const float* __restrict__ invg,
    float* __restrict__ out) {
    __shared__ unsigned char Ks[8192];

    const int tid = threadIdx.x;
    const int wv = tid >> 6, lane = tid & 63, lr = lane & 15, lg = lane >> 4;
    const int ks = blockIdx.x & (KSEG - 1);
    const int qt = (blockIdx.x >> 2) & 31;
    const int bh = blockIdx.x >> 7;

    const float* Kg = K + (size_t)bh * S_LEN * D_KD;
    const float* Mg = M + (size_t)(qt * 64) * S_LEN;
    float* attng = out + (size_t)NBH * S_LEN * D_KD +
                   (size_t)bh * S_LEN * S_LEN + (size_t)(qt * 64) * S_LEN;

    // Q A-fragment in registers (one-time; replaces Qs staging + per-tile reads)
    short8 qa0, qa1;
    {
        const float* qr = Q + ((size_t)bh * S_LEN + qt * 64 + 16 * wv + lr) * D_KD + 8 * lg;
        qa0 = pack8(*(const float4*)(qr), *(const float4*)(qr + 4));
        qa1 = pack8(*(const float4*)(qr + 32), *(const float4*)(qr + 36));
    }

    float inv[4];
#pragma unroll
    for (int r = 0; r < 4; r++)
        inv[r] = invg[(size_t)bh * S_LEN + qt * 64 + 16 * wv + 4 * lg + r];

    const int nt_kt = S_LEN / (64 * KSEG);   // 8 k-tiles per block
    const float* Kseg = Kg + (size_t)(ks * (S_LEN / KSEG)) * D_KD;

    float4 kreg[4];
    load_rm(Kseg, kreg, tid);                // prologue prefetch

    for (int kt = 0; kt < nt_kt; kt++) {
        const int key0 = ks * (S_LEN / KSEG) + kt * 64;
        write_rm(kreg, Ks, tid);             // consume prefetch
        ldsbar();                            // staging visible; stores keep flying

        if (kt + 1 < nt_kt)
            load_rm(Kseg + (size_t)(kt + 1) * 64 * D_KD, kreg, tid);

        float mreg[4][4];
#pragma unroll
        for (int r = 0; r < 4; r++) {
            const float* mrow = Mg + (size_t)(16 * wv + 4 * lg + r) * S_LEN + key0;
#pragma unroll
            for (int nt = 0; nt < 4; nt++) mreg[r][nt] = mrow[16 * nt + lr];
        }

        f32x4 acc[4] = {};
        qkt_r(qa0, qa1, Ks, lr, lg, acc);

#pragma unroll
        for (int r = 0; r < 4; r++) {
            const int row = 16 * wv + 4 * lg + r;
            float* arow = attng + (size_t)row * S_LEN + key0;
#pragma unroll
            for (int nt = 0; nt < 4; nt++) {
                float e = __expf(acc[nt][r] * 0.125f) * mreg[r][nt] * inv[r];
                __builtin_nontemporal_store(e, arow + 16 * nt + lr);
            }
        }
        ldsbar();                            // qkt ds_reads done before overwrite
    }
}

extern "C" void kernel_launch(void* const* d_in, const int* in_sizes, int n_in,
                              void* d_out, int out_size, void* d_ws, size_t ws_size,
                              hipStream_t stream) {
    const float* Q = (const float*)d_in[0];
    const float* K = (const float*)d_in[1];
    const float* V = (const float*)d_in[2];
    const float* M = (const float*)d_in[3];
    float* out = (float*)d_out;
    float* invg = (float*)d_ws;          // 64*2048 floats = 512 KB
    attn_ctx<<<dim3(NBH * 32), dim3(256), 0, stream>>>(Q, K, V, M, out, invg);
    attn_mat<<<dim3(NBH * 32 * KSEG), dim3(256), 0, stream>>>(Q, K, M, invg, out);
}